// Round 1
// baseline (642.675 us; speedup 1.0000x reference)
//
#include <hip/hip_runtime.h>
#include <hip/hip_bf16.h>
#include <stdint.h>

typedef __bf16 bf16x8 __attribute__((ext_vector_type(8)));
typedef float f32x4 __attribute__((ext_vector_type(4)));
typedef unsigned short u16;
typedef unsigned int u32;

#define DEVI __device__ __forceinline__

DEVI u16 f2b(float f){ __bf16 h = (__bf16)f; return __builtin_bit_cast(u16, h); }
DEVI float b2f(u16 u){ return (float)__builtin_bit_cast(__bf16, u); }

constexpr int BSZ = 2, SEQ = 2048, DIM = 2048, NH = 16, HD = 128;

#if defined(__has_builtin)
#if __has_builtin(__builtin_amdgcn_global_load_lds)
#define HAVE_ASYNC_LDS 1
#endif
#endif

// async global->LDS 16B copy; LDS dest must be wave-uniform-base + lane*16 (it is:
// all call sites use lds offset linear in threadIdx with stride 16B).
DEVI void cp16(void* lds, const void* g){
#ifdef HAVE_ASYNC_LDS
  auto gp = (const __attribute__((address_space(1))) u32*)(uintptr_t)g;
  auto lp = (__attribute__((address_space(3))) u32*)(uintptr_t)lds;
  __builtin_amdgcn_global_load_lds(gp, lp, 16, 0, 0);
#else
  *(uint4*)lds = *(const uint4*)g;
#endif
}

// ---------------------------------------------------------------- convert
// xb = bf16(x) [4096x2048]; wqkv = bf16([wq;wk;wv]) [6144x2048]; wob = bf16(wo)
__global__ __launch_bounds__(256) void k_convert(
    const float* __restrict__ x, const float* __restrict__ wq,
    const float* __restrict__ wk, const float* __restrict__ wv,
    const float* __restrict__ wo,
    u16* __restrict__ xb, u16* __restrict__ wqkv, u16* __restrict__ wob)
{
  int e = (blockIdx.x * 256 + threadIdx.x) * 4;   // 25165824 elements total
  float4 v; u16* dp;
  if (e < 8388608){                                // x
    v = *(const float4*)&x[e]; dp = &xb[e];
  } else if (e < 20971520){                        // wq|wk|wv packed
    int o = e - 8388608; int sec = o >> 22; int oo = o & 4194303;
    const float* w = (sec == 0) ? wq : ((sec == 1) ? wk : wv);
    v = *(const float4*)&w[oo]; dp = &wqkv[o];
  } else {                                         // wo
    int o = e - 20971520;
    v = *(const float4*)&wo[o]; dp = &wob[o];
  }
  ushort4 r; r.x = f2b(v.x); r.y = f2b(v.y); r.z = f2b(v.z); r.w = f2b(v.w);
  *(ushort4*)dp = r;
}

// ---------------------------------------------------------------- gemm QKV
// C[m,n] = sum_k A[m,k]*W[n,k]; A: 4096x2048 bf16, W: 6144x2048 bf16.
// Epilogue scatters into Q/K/V laid out (B,NH,S,HD) bf16.
__global__ __launch_bounds__(256) void k_gemm_qkv(
    const u16* __restrict__ A, const u16* __restrict__ W,
    u16* __restrict__ Qd, u16* __restrict__ Kd, u16* __restrict__ Vd)
{
  __shared__ u16 As[128*32];
  __shared__ u16 Bs[128*32];
  const int t = threadIdx.x;
  const int lane = t & 63;
  const int l15 = lane & 15, quad = lane >> 4;
  const int wave = t >> 6;
  const int wr = (wave >> 1) * 64, wc = (wave & 1) * 64;
  const int tm = blockIdx.y * 128, tn = blockIdx.x * 128;
  const int arow = t >> 2, acol = (t & 3) * 8;

  f32x4 acc[4][4] = {};
  for (int k0 = 0; k0 < DIM; k0 += 32){
    __syncthreads();
    #pragma unroll
    for (int is = 0; is < 2; ++is){
      int row = is*64 + arow;
      cp16(&As[is*2048 + t*8], &A[(size_t)(tm + row)*DIM + k0 + acol]);
      cp16(&Bs[is*2048 + t*8], &W[(size_t)(tn + row)*DIM + k0 + acol]);
    }
    __syncthreads();
    bf16x8 af[4], bf[4];
    #pragma unroll
    for (int i = 0; i < 4; ++i){
      af[i] = *(const bf16x8*)&As[(wr + i*16 + l15)*32 + quad*8];
      bf[i] = *(const bf16x8*)&Bs[(wc + i*16 + l15)*32 + quad*8];
    }
    #pragma unroll
    for (int mt = 0; mt < 4; ++mt)
      #pragma unroll
      for (int nt = 0; nt < 4; ++nt)
        acc[mt][nt] = __builtin_amdgcn_mfma_f32_16x16x32_bf16(af[mt], bf[nt], acc[mt][nt], 0, 0, 0);
  }
  #pragma unroll
  for (int mt = 0; mt < 4; ++mt)
    #pragma unroll
    for (int nt = 0; nt < 4; ++nt)
      #pragma unroll
      for (int r = 0; r < 4; ++r){
        int row = tm + wr + mt*16 + quad*4 + r;           // m = b*SEQ + s
        int col = tn + wc + nt*16 + l15;                  // n in [0,6144)
        int sec = col >> 11, nn = col & 2047;
        int h = nn >> 7, d = nn & 127;
        int b = row >> 11, s = row & 2047;
        u16* dst = (sec == 0) ? Qd : ((sec == 1) ? Kd : Vd);
        dst[(((size_t)(b*NH + h))*SEQ + s)*HD + d] = f2b(acc[mt][nt][r]);
      }
}

// ---------------------------------------------------------------- rope (in place)
// Q additionally scaled by (1/sqrt(HD))*log2(e) so flash can use exp2.
__global__ __launch_bounds__(256) void k_rope(
    u16* __restrict__ Qd, u16* __restrict__ Kd,
    const float* __restrict__ fc, const float* __restrict__ fs)
{
  int p = blockIdx.x * 256 + threadIdx.x;   // 8388608 pairs (Q then K)
  int isK = p >> 22;
  int pi = p & 4194303;
  int bh = pi >> 17;
  int rem = pi & 131071;
  int s = rem >> 6, i = rem & 63;
  u16* ptr = isK ? Kd : Qd;
  float scale = isK ? 1.0f : (0.08838834764831845f * 1.4426950408889634f);
  size_t base = ((size_t)bh*SEQ + s)*HD + 2*i;
  float v0 = b2f(ptr[base]), v1 = b2f(ptr[base + 1]);
  float c = fc[s*64 + i], sn = fs[s*64 + i];
  ptr[base]     = f2b((v0*c - v1*sn) * scale);
  ptr[base + 1] = f2b((v0*sn + v1*c) * scale);
}

// ---------------------------------------------------------------- flash attention
// grid (S/128, NH, B), 256 thr. Wave w owns Q rows [w*32,w*32+32). BN=64 keys/tile.
__global__ __launch_bounds__(256) void k_flash(
    const u16* __restrict__ Qd, const u16* __restrict__ Kd,
    const u16* __restrict__ Vd, u16* __restrict__ Od)
{
  __shared__ u16 Ks[64*144];     // key rows, stride 144 el (pad for bank spread)
  __shared__ u16 Vts[128*72];    // V transposed: [d][key], stride 72 el
  __shared__ u16 Ps[4*32*72];    // per-wave P tile 32x64, stride 72 el

  const int t = threadIdx.x, lane = t & 63, wave = t >> 6;
  const int l15 = lane & 15, quad = lane >> 4;
  const int bx = blockIdx.x, h = blockIdx.y, b = blockIdx.z;
  const int bh = b*NH + h;
  const int q0 = bx * 128;
  const int qbase = q0 + wave*32;
  const size_t base = (size_t)bh * SEQ * HD;

  // Q fragments in registers (A-operand layout), reused across all k-tiles
  bf16x8 qf[2][4];
  #pragma unroll
  for (int mt = 0; mt < 2; ++mt)
    #pragma unroll
    for (int ks = 0; ks < 4; ++ks)
      qf[mt][ks] = *(const bf16x8*)&Qd[base + (size_t)(qbase + mt*16 + l15)*HD + ks*32 + quad*8];

  f32x4 oacc[2][8] = {};
  float m_r[2][4], l_r[2][4];
  #pragma unroll
  for (int mt = 0; mt < 2; ++mt)
    #pragma unroll
    for (int r = 0; r < 4; ++r){ m_r[mt][r] = -1e30f; l_r[mt][r] = 0.f; }

  u16* Psw = &Ps[wave*32*72];
  const int nkt = 2*bx + 2;
  for (int kt = 0; kt < nkt; ++kt){
    __syncthreads();
    { // stage K tile 64x128 -> Ks (stride 144)
      int rb = t >> 4, cb = (t & 15) * 8;
      #pragma unroll
      for (int i = 0; i < 4; ++i){
        int row = i*16 + rb;
        uint4 v = *(const uint4*)&Kd[base + (size_t)(kt*64 + row)*HD + cb];
        *(uint4*)&Ks[row*144 + cb] = v;
      }
      // stage V transposed: lane = key index -> conflict-free u16 scatter
      int sk = t & 63, g = t >> 6;
      #pragma unroll
      for (int i = 0; i < 4; ++i){
        int d0 = g*8 + i*32;
        uint4 v = *(const uint4*)&Vd[base + (size_t)(kt*64 + sk)*HD + d0];
        const u16* pv = (const u16*)&v;
        #pragma unroll
        for (int j = 0; j < 8; ++j) Vts[(d0 + j)*72 + sk] = pv[j];
      }
    }
    __syncthreads();

    if (kt*64 <= qbase + 31){            // wave-uniform: tile has visible keys
      f32x4 sacc[2][4] = {};
      #pragma unroll
      for (int ks = 0; ks < 4; ++ks){
        bf16x8 kf[4];
        #pragma unroll
        for (int nt = 0; nt < 4; ++nt)
          kf[nt] = *(const bf16x8*)&Ks[(nt*16 + l15)*144 + ks*32 + quad*8];
        #pragma unroll
        for (int mt = 0; mt < 2; ++mt)
          #pragma unroll
          for (int nt = 0; nt < 4; ++nt)
            sacc[mt][nt] = __builtin_amdgcn_mfma_f32_16x16x32_bf16(qf[mt][ks], kf[nt], sacc[mt][nt], 0, 0, 0);
      }
      // causal mask
      #pragma unroll
      for (int mt = 0; mt < 2; ++mt)
        #pragma unroll
        for (int nt = 0; nt < 4; ++nt){
          int key = kt*64 + nt*16 + l15;
          #pragma unroll
          for (int r = 0; r < 4; ++r){
            int qrow = qbase + mt*16 + quad*4 + r;
            if (key > qrow) sacc[mt][nt][r] = -1e30f;
          }
        }
      // online softmax (rows live in reg r x 16-lane col groups)
      #pragma unroll
      for (int mt = 0; mt < 2; ++mt)
        #pragma unroll
        for (int r = 0; r < 4; ++r){
          float rm = fmaxf(fmaxf(sacc[mt][0][r], sacc[mt][1][r]),
                           fmaxf(sacc[mt][2][r], sacc[mt][3][r]));
          rm = fmaxf(rm, __shfl_xor(rm, 1));
          rm = fmaxf(rm, __shfl_xor(rm, 2));
          rm = fmaxf(rm, __shfl_xor(rm, 4));
          rm = fmaxf(rm, __shfl_xor(rm, 8));
          float mnew = fmaxf(m_r[mt][r], rm);
          float alpha = exp2f(m_r[mt][r] - mnew);
          m_r[mt][r] = mnew;
          float rs = 0.f;
          #pragma unroll
          for (int nt = 0; nt < 4; ++nt){
            float p = exp2f(sacc[mt][nt][r] - mnew);
            sacc[mt][nt][r] = p;
            rs += p;
          }
          rs += __shfl_xor(rs, 1); rs += __shfl_xor(rs, 2);
          rs += __shfl_xor(rs, 4); rs += __shfl_xor(rs, 8);
          l_r[mt][r] = l_r[mt][r]*alpha + rs;
          #pragma unroll
          for (int nt = 0; nt < 8; ++nt) oacc[mt][nt][r] *= alpha;
          #pragma unroll
          for (int nt = 0; nt < 4; ++nt)
            Psw[(mt*16 + quad*4 + r)*72 + nt*16 + l15] = f2b(sacc[mt][nt][r]);
        }
      // O += P*V  (P from wave-private LDS in A-layout; Vts rows are d)
      #pragma unroll
      for (int ks2 = 0; ks2 < 2; ++ks2){
        bf16x8 pf[2];
        #pragma unroll
        for (int mt = 0; mt < 2; ++mt)
          pf[mt] = *(const bf16x8*)&Psw[(mt*16 + l15)*72 + ks2*32 + quad*8];
        #pragma unroll
        for (int nt = 0; nt < 8; ++nt){
          bf16x8 vf = *(const bf16x8*)&Vts[(nt*16 + l15)*72 + ks2*32 + quad*8];
          #pragma unroll
          for (int mt = 0; mt < 2; ++mt)
            oacc[mt][nt] = __builtin_amdgcn_mfma_f32_16x16x32_bf16(pf[mt], vf, oacc[mt][nt], 0, 0, 0);
        }
      }
    }
  }
  // epilogue: O/l -> Od laid out (B,S,NH,HD) = row-major 4096x2048
  #pragma unroll
  for (int mt = 0; mt < 2; ++mt){
    float inv[4];
    #pragma unroll
    for (int r = 0; r < 4; ++r) inv[r] = 1.0f / l_r[mt][r];
    #pragma unroll
    for (int nt = 0; nt < 8; ++nt)
      #pragma unroll
      for (int r = 0; r < 4; ++r){
        int s = qbase + mt*16 + quad*4 + r;
        int d = nt*16 + l15;
        Od[(((size_t)(b*SEQ + s))*NH + h)*HD + d] = f2b(oacc[mt][nt][r] * inv[r]);
      }
  }
}

// ---------------------------------------------------------------- out proj
// out[m,n] = sum_k O[m,k]*wo[n,k]; fp32 output.
__global__ __launch_bounds__(256) void k_gemm_out(
    const u16* __restrict__ A, const u16* __restrict__ W, float* __restrict__ out)
{
  __shared__ u16 As[128*32];
  __shared__ u16 Bs[128*32];
  const int t = threadIdx.x;
  const int lane = t & 63;
  const int l15 = lane & 15, quad = lane >> 4;
  const int wave = t >> 6;
  const int wr = (wave >> 1) * 64, wc = (wave & 1) * 64;
  const int tm = blockIdx.y * 128, tn = blockIdx.x * 128;
  const int arow = t >> 2, acol = (t & 3) * 8;

  f32x4 acc[4][4] = {};
  for (int k0 = 0; k0 < DIM; k0 += 32){
    __syncthreads();
    #pragma unroll
    for (int is = 0; is < 2; ++is){
      int row = is*64 + arow;
      cp16(&As[is*2048 + t*8], &A[(size_t)(tm + row)*DIM + k0 + acol]);
      cp16(&Bs[is*2048 + t*8], &W[(size_t)(tn + row)*DIM + k0 + acol]);
    }
    __syncthreads();
    bf16x8 af[4], bf[4];
    #pragma unroll
    for (int i = 0; i < 4; ++i){
      af[i] = *(const bf16x8*)&As[(wr + i*16 + l15)*32 + quad*8];
      bf[i] = *(const bf16x8*)&Bs[(wc + i*16 + l15)*32 + quad*8];
    }
    #pragma unroll
    for (int mt = 0; mt < 4; ++mt)
      #pragma unroll
      for (int nt = 0; nt < 4; ++nt)
        acc[mt][nt] = __builtin_amdgcn_mfma_f32_16x16x32_bf16(af[mt], bf[nt], acc[mt][nt], 0, 0, 0);
  }
  #pragma unroll
  for (int mt = 0; mt < 4; ++mt)
    #pragma unroll
    for (int nt = 0; nt < 4; ++nt)
      #pragma unroll
      for (int r = 0; r < 4; ++r){
        int row = tm + wr + mt*16 + quad*4 + r;
        int col = tn + wc + nt*16 + l15;
        out[(size_t)row*DIM + col] = acc[mt][nt][r];
      }
}

// ---------------------------------------------------------------- launch
extern "C" void kernel_launch(void* const* d_in, const int* in_sizes, int n_in,
                              void* d_out, int out_size, void* d_ws, size_t ws_size,
                              hipStream_t stream)
{
  const float* x  = (const float*)d_in[0];
  const float* wq = (const float*)d_in[1];
  const float* wk = (const float*)d_in[2];
  const float* wv = (const float*)d_in[3];
  const float* wo = (const float*)d_in[4];
  const float* fc = (const float*)d_in[5];
  const float* fs = (const float*)d_in[6];
  float* out = (float*)d_out;

  char* ws = (char*)d_ws;
  u16* xb   = (u16*)(ws);                 // 16 MB  bf16 x         [4096x2048]
  u16* wqkv = (u16*)(ws + 16777216);      // 24 MB  bf16 [wq;wk;wv][6144x2048]
  u16* wob  = (u16*)(ws + 41943040);      //  8 MB  bf16 wo        [2048x2048]
  u16* Qr   = (u16*)(ws + 50331648);      // 16 MB  (B,NH,S,HD)
  u16* Kr   = (u16*)(ws + 67108864);      // 16 MB
  u16* Vr   = (u16*)(ws + 83886080);      // 16 MB
  u16* Ob   = (u16*)(ws + 100663296);     // 16 MB  (B,S,NH,HD) = 4096x2048
  // total ws use: 117,440,512 bytes

  k_convert <<<24576, 256, 0, stream>>>(x, wq, wk, wv, wo, xb, wqkv, wob);
  k_gemm_qkv<<<dim3(48, 32), 256, 0, stream>>>(xb, wqkv, Qr, Kr, Vr);
  k_rope    <<<32768, 256, 0, stream>>>(Qr, Kr, fc, fs);
  k_flash   <<<dim3(16, NH, BSZ), 256, 0, stream>>>(Qr, Kr, Vr, Ob);
  k_gemm_out<<<dim3(16, 32), 256, 0, stream>>>(Ob, wob, out);
}

// Round 2
// 470.504 us; speedup vs baseline: 1.3659x; 1.3659x over previous
//
#include <hip/hip_runtime.h>
#include <hip/hip_bf16.h>
#include <stdint.h>

typedef __bf16 bf16x8 __attribute__((ext_vector_type(8)));
typedef float f32x4 __attribute__((ext_vector_type(4)));
typedef unsigned short u16;
typedef unsigned int u32;

#define DEVI __device__ __forceinline__

DEVI u16 f2b(float f){ __bf16 h = (__bf16)f; return __builtin_bit_cast(u16, h); }
DEVI float b2f(u16 u){ return (float)__builtin_bit_cast(__bf16, u); }

constexpr int BSZ = 2, SEQ = 2048, DIM = 2048, NH = 16, HD = 128;

#if defined(__has_builtin)
#if __has_builtin(__builtin_amdgcn_global_load_lds)
#define HAVE_ASYNC_LDS 1
#endif
#endif

// async global->LDS 16B copy; LDS dest is wave-uniform base + lane*16 at all call sites.
DEVI void cp16(void* lds, const void* g){
#ifdef HAVE_ASYNC_LDS
  auto gp = (const __attribute__((address_space(1))) u32*)(uintptr_t)g;
  auto lp = (__attribute__((address_space(3))) u32*)(uintptr_t)lds;
  __builtin_amdgcn_global_load_lds(gp, lp, 16, 0, 0);
#else
  *(uint4*)lds = *(const uint4*)g;
#endif
}

// ---------------------------------------------------------------- convert
__global__ __launch_bounds__(256) void k_convert(
    const float* __restrict__ x, const float* __restrict__ wq,
    const float* __restrict__ wk, const float* __restrict__ wv,
    const float* __restrict__ wo,
    u16* __restrict__ xb, u16* __restrict__ wqkv, u16* __restrict__ wob)
{
  int e = (blockIdx.x * 256 + threadIdx.x) * 4;
  float4 v; u16* dp;
  if (e < 8388608){
    v = *(const float4*)&x[e]; dp = &xb[e];
  } else if (e < 20971520){
    int o = e - 8388608; int sec = o >> 22; int oo = o & 4194303;
    const float* w = (sec == 0) ? wq : ((sec == 1) ? wk : wv);
    v = *(const float4*)&w[oo]; dp = &wqkv[o];
  } else {
    int o = e - 20971520;
    v = *(const float4*)&wo[o]; dp = &wob[o];
  }
  ushort4 r; r.x = f2b(v.x); r.y = f2b(v.y); r.z = f2b(v.z); r.w = f2b(v.w);
  *(ushort4*)dp = r;
}

// ---------------------------------------------------------------- gemm QKV
__global__ __launch_bounds__(256) void k_gemm_qkv(
    const u16* __restrict__ A, const u16* __restrict__ W,
    u16* __restrict__ Qd, u16* __restrict__ Kd, u16* __restrict__ Vd)
{
  __shared__ u16 As[128*32];
  __shared__ u16 Bs[128*32];
  const int t = threadIdx.x;
  const int lane = t & 63;
  const int l15 = lane & 15, quad = lane >> 4;
  const int wave = t >> 6;
  const int wr = (wave >> 1) * 64, wc = (wave & 1) * 64;
  const int tm = blockIdx.y * 128, tn = blockIdx.x * 128;
  const int arow = t >> 2, acol = (t & 3) * 8;

  f32x4 acc[4][4] = {};
  for (int k0 = 0; k0 < DIM; k0 += 32){
    __syncthreads();
    #pragma unroll
    for (int is = 0; is < 2; ++is){
      int row = is*64 + arow;
      cp16(&As[is*2048 + t*8], &A[(size_t)(tm + row)*DIM + k0 + acol]);
      cp16(&Bs[is*2048 + t*8], &W[(size_t)(tn + row)*DIM + k0 + acol]);
    }
    __syncthreads();
    bf16x8 af[4], bf[4];
    #pragma unroll
    for (int i = 0; i < 4; ++i){
      af[i] = *(const bf16x8*)&As[(wr + i*16 + l15)*32 + quad*8];
      bf[i] = *(const bf16x8*)&Bs[(wc + i*16 + l15)*32 + quad*8];
    }
    #pragma unroll
    for (int mt = 0; mt < 4; ++mt)
      #pragma unroll
      for (int nt = 0; nt < 4; ++nt)
        acc[mt][nt] = __builtin_amdgcn_mfma_f32_16x16x32_bf16(af[mt], bf[nt], acc[mt][nt], 0, 0, 0);
  }
  #pragma unroll
  for (int mt = 0; mt < 4; ++mt)
    #pragma unroll
    for (int nt = 0; nt < 4; ++nt)
      #pragma unroll
      for (int r = 0; r < 4; ++r){
        int row = tm + wr + mt*16 + quad*4 + r;
        int col = tn + wc + nt*16 + l15;
        int sec = col >> 11, nn = col & 2047;
        int h = nn >> 7, d = nn & 127;
        int b = row >> 11, s = row & 2047;
        u16* dst = (sec == 0) ? Qd : ((sec == 1) ? Kd : Vd);
        dst[(((size_t)(b*NH + h))*SEQ + s)*HD + d] = f2b(acc[mt][nt][r]);
      }
}

// ---------------------------------------------------------------- rope (in place)
// Q additionally scaled by (1/sqrt(HD))*log2(e) so flash can use exp2.
__global__ __launch_bounds__(256) void k_rope(
    u16* __restrict__ Qd, u16* __restrict__ Kd,
    const float* __restrict__ fc, const float* __restrict__ fs)
{
  int p = blockIdx.x * 256 + threadIdx.x;
  int isK = p >> 22;
  int pi = p & 4194303;
  int bh = pi >> 17;
  int rem = pi & 131071;
  int s = rem >> 6, i = rem & 63;
  u16* ptr = isK ? Kd : Qd;
  float scale = isK ? 1.0f : (0.08838834764831845f * 1.4426950408889634f);
  size_t base = ((size_t)bh*SEQ + s)*HD + 2*i;
  float v0 = b2f(ptr[base]), v1 = b2f(ptr[base + 1]);
  float c = fc[s*64 + i], sn = fs[s*64 + i];
  ptr[base]     = f2b((v0*c - v1*sn) * scale);
  ptr[base + 1] = f2b((v0*sn + v1*c) * scale);
}

// ---------------------------------------------------------------- V transpose
// V (B,NH,S,HD) -> Vt (B,NH,HD,S). Tiles of 64s x 64d via padded LDS.
__global__ __launch_bounds__(256) void k_vtrans(
    const u16* __restrict__ V, u16* __restrict__ Vt)
{
  __shared__ u16 ts[64*72];
  const int t = threadIdx.x;
  const int st = blockIdx.x, dt = blockIdx.y, bh = blockIdx.z;
  const size_t base  = (size_t)bh * SEQ * HD;
  const size_t baseT = (size_t)bh * HD * SEQ;
  #pragma unroll
  for (int i = 0; i < 2; ++i){
    int s = i*32 + (t>>3), c = t&7;
    *(uint4*)&ts[s*72 + c*8] = *(const uint4*)&V[base + (size_t)(st*64 + s)*HD + dt*64 + c*8];
  }
  __syncthreads();
  #pragma unroll
  for (int i = 0; i < 2; ++i){
    int d = i*32 + (t>>3), sc = t&7;
    u16 tmp[8];
    #pragma unroll
    for (int j = 0; j < 8; ++j) tmp[j] = ts[(sc*8 + j)*72 + d];
    *(uint4*)&Vt[baseT + (size_t)(dt*64 + d)*SEQ + st*64 + sc*8] = *(const uint4*)tmp;
  }
}

// ---------------------------------------------------------------- flash attention
// grid (8, NH, B): block handles q-tiles {j, 15-j} (uniform 36 k-tiles).
// Computes S^T = K.Q^T so softmax reduces mostly in-register; O^T = V^T.P^T.
__global__ __launch_bounds__(256) void k_flash(
    const u16* __restrict__ Qd, const u16* __restrict__ Kd,
    const u16* __restrict__ Vt, u16* __restrict__ Od)
{
  __shared__ u16 Ks[64*144];     // [key][d], stride 144
  __shared__ u16 Vs[128*72];     // [d][key], stride 72
  __shared__ u16 Ps[4*32*72];    // per-wave P [query][key], stride 72

  const int t = threadIdx.x, lane = t & 63, wave = t >> 6;
  const int l15 = lane & 15, quad = lane >> 4;
  const int h = blockIdx.y, b = blockIdx.z, bh = b*NH + h;
  const size_t base  = (size_t)bh * SEQ * HD;
  const size_t baseT = (size_t)bh * HD * SEQ;
  u16* Psw = &Ps[wave*32*72];

  const int krow = t >> 4, kcol = (t & 15) * 8;   // K stage rows +i*16
  const int vrow = t >> 3, vcol = (t & 7) * 8;    // V stage rows +i*32

  for (int pass = 0; pass < 2; ++pass){
    const int qt = pass ? (15 - (int)blockIdx.x) : (int)blockIdx.x;
    const int qb = qt*128 + wave*32;
    const int nkt = 2*qt + 2;

    // Q fragments (B-operand rows), reused across all k-tiles of this pass
    bf16x8 qf[2][4];
    #pragma unroll
    for (int mt = 0; mt < 2; ++mt)
      #pragma unroll
      for (int ks = 0; ks < 4; ++ks)
        qf[mt][ks] = *(const bf16x8*)&Qd[base + (size_t)(qb + mt*16 + l15)*HD + ks*32 + quad*8];

    f32x4 oacc[8][2] = {};
    float m_s[2] = {-1e30f, -1e30f}, l_s[2] = {0.f, 0.f};

    // prologue: prefetch tile 0
    uint4 kreg[4], vreg[4];
    #pragma unroll
    for (int i = 0; i < 4; ++i){
      kreg[i] = *(const uint4*)&Kd[base + (size_t)(i*16 + krow)*HD + kcol];
      vreg[i] = *(const uint4*)&Vt[baseT + (size_t)(i*32 + vrow)*SEQ + vcol];
    }

    for (int kt = 0; kt < nkt; ++kt){
      __syncthreads();
      #pragma unroll
      for (int i = 0; i < 4; ++i){
        *(uint4*)&Ks[(i*16 + krow)*144 + kcol] = kreg[i];
        *(uint4*)&Vs[(i*32 + vrow)*72 + vcol] = vreg[i];
      }
      __syncthreads();
      if (kt + 1 < nkt){   // prefetch next tile (hides global latency under compute)
        #pragma unroll
        for (int i = 0; i < 4; ++i){
          kreg[i] = *(const uint4*)&Kd[base + (size_t)((kt+1)*64 + i*16 + krow)*HD + kcol];
          vreg[i] = *(const uint4*)&Vt[baseT + (size_t)(i*32 + vrow)*SEQ + (kt+1)*64 + vcol];
        }
      }
      if (kt*64 <= qb + 31){   // wave-uniform guard
        f32x4 sacc[4][2] = {};   // [key-block][query-block], D[key][query]
        #pragma unroll
        for (int ks = 0; ks < 4; ++ks){
          bf16x8 kf[4];
          #pragma unroll
          for (int nk = 0; nk < 4; ++nk)
            kf[nk] = *(const bf16x8*)&Ks[(nk*16 + l15)*144 + ks*32 + quad*8];
          #pragma unroll
          for (int nk = 0; nk < 4; ++nk)
            #pragma unroll
            for (int mt = 0; mt < 2; ++mt)
              sacc[nk][mt] = __builtin_amdgcn_mfma_f32_16x16x32_bf16(kf[nk], qf[mt][ks], sacc[nk][mt], 0, 0, 0);
        }
        // causal mask: key (row/reg dim) > query (lane dim) -> -inf
        #pragma unroll
        for (int nk = 0; nk < 4; ++nk)
          #pragma unroll
          for (int mt = 0; mt < 2; ++mt){
            int q = qb + mt*16 + l15;
            #pragma unroll
            for (int r = 0; r < 4; ++r){
              int key = kt*64 + nk*16 + quad*4 + r;
              if (key > q) sacc[nk][mt][r] = -1e30f;
            }
          }
        // online softmax: per-lane over 16 regs, then 2 shuffles across quads
        #pragma unroll
        for (int mt = 0; mt < 2; ++mt){
          float rm = -1e30f;
          #pragma unroll
          for (int nk = 0; nk < 4; ++nk)
            #pragma unroll
            for (int r = 0; r < 4; ++r) rm = fmaxf(rm, sacc[nk][mt][r]);
          rm = fmaxf(rm, __shfl_xor(rm, 16));
          rm = fmaxf(rm, __shfl_xor(rm, 32));
          float mnew = fmaxf(m_s[mt], rm);
          float alpha = exp2f(m_s[mt] - mnew);
          m_s[mt] = mnew;
          float rs = 0.f;
          #pragma unroll
          for (int nk = 0; nk < 4; ++nk){
            u16 pk[4];
            #pragma unroll
            for (int r = 0; r < 4; ++r){
              float p = exp2f(sacc[nk][mt][r] - mnew);
              rs += p;
              pk[r] = f2b(p);
            }
            *(uint2*)&Psw[(mt*16 + l15)*72 + nk*16 + quad*4] = *(const uint2*)pk;
          }
          rs += __shfl_xor(rs, 16);
          rs += __shfl_xor(rs, 32);
          l_s[mt] = l_s[mt]*alpha + rs;
          #pragma unroll
          for (int db = 0; db < 8; ++db)
            #pragma unroll
            for (int r = 0; r < 4; ++r) oacc[db][mt][r] *= alpha;
        }
        // O^T += V^T . P^T
        #pragma unroll
        for (int k2 = 0; k2 < 2; ++k2){
          bf16x8 pf[2];
          #pragma unroll
          for (int mt = 0; mt < 2; ++mt)
            pf[mt] = *(const bf16x8*)&Psw[(mt*16 + l15)*72 + k2*32 + quad*8];
          #pragma unroll
          for (int db = 0; db < 8; ++db){
            bf16x8 vf = *(const bf16x8*)&Vs[(db*16 + l15)*72 + k2*32 + quad*8];
            #pragma unroll
            for (int mt = 0; mt < 2; ++mt)
              oacc[db][mt] = __builtin_amdgcn_mfma_f32_16x16x32_bf16(vf, pf[mt], oacc[db][mt], 0, 0, 0);
          }
        }
      }
    }
    // epilogue: O^T C-layout -> Od (B,S,NH,HD); 4 consecutive d per reg -> b64 stores
    #pragma unroll
    for (int mt = 0; mt < 2; ++mt){
      float inv = 1.0f / l_s[mt];
      int s = qb + mt*16 + l15;
      #pragma unroll
      for (int db = 0; db < 8; ++db){
        u16 ok[4];
        #pragma unroll
        for (int r = 0; r < 4; ++r) ok[r] = f2b(oacc[db][mt][r] * inv);
        *(uint2*)&Od[(((size_t)(b*SEQ + s))*NH + h)*HD + db*16 + quad*4] = *(const uint2*)ok;
      }
    }
  }
}

// ---------------------------------------------------------------- out proj
__global__ __launch_bounds__(256) void k_gemm_out(
    const u16* __restrict__ A, const u16* __restrict__ W, float* __restrict__ out)
{
  __shared__ u16 As[128*32];
  __shared__ u16 Bs[128*32];
  const int t = threadIdx.x;
  const int lane = t & 63;
  const int l15 = lane & 15, quad = lane >> 4;
  const int wave = t >> 6;
  const int wr = (wave >> 1) * 64, wc = (wave & 1) * 64;
  const int tm = blockIdx.y * 128, tn = blockIdx.x * 128;
  const int arow = t >> 2, acol = (t & 3) * 8;

  f32x4 acc[4][4] = {};
  for (int k0 = 0; k0 < DIM; k0 += 32){
    __syncthreads();
    #pragma unroll
    for (int is = 0; is < 2; ++is){
      int row = is*64 + arow;
      cp16(&As[is*2048 + t*8], &A[(size_t)(tm + row)*DIM + k0 + acol]);
      cp16(&Bs[is*2048 + t*8], &W[(size_t)(tn + row)*DIM + k0 + acol]);
    }
    __syncthreads();
    bf16x8 af[4], bf[4];
    #pragma unroll
    for (int i = 0; i < 4; ++i){
      af[i] = *(const bf16x8*)&As[(wr + i*16 + l15)*32 + quad*8];
      bf[i] = *(const bf16x8*)&Bs[(wc + i*16 + l15)*32 + quad*8];
    }
    #pragma unroll
    for (int mt = 0; mt < 4; ++mt)
      #pragma unroll
      for (int nt = 0; nt < 4; ++nt)
        acc[mt][nt] = __builtin_amdgcn_mfma_f32_16x16x32_bf16(af[mt], bf[nt], acc[mt][nt], 0, 0, 0);
  }
  #pragma unroll
  for (int mt = 0; mt < 4; ++mt)
    #pragma unroll
    for (int nt = 0; nt < 4; ++nt)
      #pragma unroll
      for (int r = 0; r < 4; ++r){
        int row = tm + wr + mt*16 + quad*4 + r;
        int col = tn + wc + nt*16 + l15;
        out[(size_t)row*DIM + col] = acc[mt][nt][r];
      }
}

// ---------------------------------------------------------------- launch
extern "C" void kernel_launch(void* const* d_in, const int* in_sizes, int n_in,
                              void* d_out, int out_size, void* d_ws, size_t ws_size,
                              hipStream_t stream)
{
  const float* x  = (const float*)d_in[0];
  const float* wq = (const float*)d_in[1];
  const float* wk = (const float*)d_in[2];
  const float* wv = (const float*)d_in[3];
  const float* wo = (const float*)d_in[4];
  const float* fc = (const float*)d_in[5];
  const float* fs = (const float*)d_in[6];
  float* out = (float*)d_out;

  char* ws = (char*)d_ws;
  u16* xb   = (u16*)(ws);                 // 16 MB  bf16 x; reused as Vt after gemm_qkv
  u16* wqkv = (u16*)(ws + 16777216);      // 24 MB
  u16* wob  = (u16*)(ws + 41943040);      //  8 MB
  u16* Qr   = (u16*)(ws + 50331648);      // 16 MB  (B,NH,S,HD)
  u16* Kr   = (u16*)(ws + 67108864);      // 16 MB
  u16* Vr   = (u16*)(ws + 83886080);      // 16 MB
  u16* Ob   = (u16*)(ws + 100663296);     // 16 MB  (B,S,NH,HD)
  u16* VtT  = xb;                         // alias: xb dead after k_gemm_qkv

  k_convert <<<24576, 256, 0, stream>>>(x, wq, wk, wv, wo, xb, wqkv, wob);
  k_gemm_qkv<<<dim3(48, 32), 256, 0, stream>>>(xb, wqkv, Qr, Kr, Vr);
  k_rope    <<<32768, 256, 0, stream>>>(Qr, Kr, fc, fs);
  k_vtrans  <<<dim3(32, 2, 32), 256, 0, stream>>>(Vr, VtT);
  k_flash   <<<dim3(8, NH, BSZ), 256, 0, stream>>>(Qr, Kr, VtT, Ob);
  k_gemm_out<<<dim3(16, 32), 256, 0, stream>>>(Ob, wob, out);
}